// Round 4
// baseline (424.613 us; speedup 1.0000x reference)
//
#include <hip/hip_runtime.h>

// Model dims (fixed by the problem)
#define TT    128
#define CC    64
#define HH    4
#define SS    16
#define D4    256     // 4*C
#define HID_  256
#define VV    32000
#define NPE_  4
#define RR    256     // B*T

__device__ __forceinline__ float wred_sum(float v) {
#pragma unroll
    for (int off = 32; off; off >>= 1) v += __shfl_xor(v, off, 64);
    return v;
}
__device__ __forceinline__ float wred_max(float v) {
#pragma unroll
    for (int off = 32; off; off >>= 1) v = fmaxf(v, __shfl_xor(v, off, 64));
    return v;
}
__device__ __forceinline__ float sigm(float x) { return 1.f / (1.f + __expf(-x)); }

// ================= embed + all positional embeddings (fused) =================
// blocks 0..511: pos (p = blk>>7, t = blk&127); blocks 512..767: embed rows
__global__ void k_embed_pos(const int* __restrict__ idx, const float* __restrict__ tok,
                            const float* __restrict__ pe_tab, const float* __restrict__ W1,
                            const float* __restrict__ b1, const float* __restrict__ W2,
                            const float* __restrict__ b2, const float* __restrict__ g,
                            const float* __restrict__ bb,
                            float* __restrict__ x, float* __restrict__ pos) {
    int blk = blockIdx.x, c = threadIdx.x;
    if (blk >= 512) {                       // token embedding
        int r = blk - 512;
        x[r * CC + c] = tok[idx[r] * CC + c];
        return;
    }
    int p = blk >> 7, t = blk & 127;
    __shared__ float s_pe[CC], s_h[CC];
    s_pe[c] = pe_tab[(p * TT + t) * CC + c];
    __syncthreads();
    const float* w1 = W1 + p * CC * CC;
    float a = b1[p * CC + c];
    for (int k = 0; k < CC; k++) a += s_pe[k] * w1[k * CC + c];
    s_h[c] = sigm(a);
    __syncthreads();
    const float* w2 = W2 + p * CC * CC;
    float o = b2[p * CC + c];
    for (int k = 0; k < CC; k++) o += s_h[k] * w2[k * CC + c];
    float m = wred_sum(o) * (1.f / CC);
    float d = o - m;
    float var = wred_sum(d * d) * (1.f / CC);
    pos[(p * TT + t) * CC + c] =
        d * rsqrtf(var + 1e-5f) * g[p * CC + c] + bb[p * CC + c];
}

// ================= stage A: (LN1 inline) + K/Q projection + V projection =====
// blocks 0..255: K/Q mm (rg = blk&31 -> 8 rows, kq = (blk>>5)&1, h = blk>>6)
// blocks 256..263: V projection, 32 rows each (LN1 recomputed inline)
__global__ void __launch_bounds__(256) k_stageA(
    const float* __restrict__ x, const float* __restrict__ pos_p,
    const float* __restrict__ ln1g, const float* __restrict__ ln1b,
    const float* __restrict__ attW1, const float* __restrict__ valW,
    float* __restrict__ Kp, float* __restrict__ Qp, float* __restrict__ v) {
    int blk = blockIdx.x, tid = threadIdx.x;
    int lane = tid & 63, wv = tid >> 6;
    if (blk < 256) {
        int rg = blk & 31, kq = (blk >> 5) & 1, h = blk >> 6;
        int r0 = rg * 8;
        __shared__ float x1[8][128];
        // LN half (cols 64..127): wave w handles rows w and w+4
#pragma unroll
        for (int pass = 0; pass < 2; ++pass) {
            int rr = wv + pass * 4;
            float xv = x[(r0 + rr) * CC + lane];
            float m = wred_sum(xv) * (1.f / CC);
            float d = xv - m;
            float var = wred_sum(d * d) * (1.f / CC);
            x1[rr][64 + lane] = d * rsqrtf(var + 1e-5f) * ln1g[lane] + ln1b[lane];
        }
        // pos half (cols 0..63)
        for (int e = tid; e < 512; e += 256) {
            int rr = e >> 6, cc = e & 63;
            int t = (r0 + rr) & (TT - 1);
            x1[rr][cc] = pos_p[t * CC + cc];
        }
        __syncthreads();
        const float* w = attW1 + (h * D4 + kq * 128) * D4;
        float acc[8] = {0, 0, 0, 0, 0, 0, 0, 0};
        for (int c = 0; c < 128; c++) {
            float wvv = w[c * D4 + tid];
#pragma unroll
            for (int rr = 0; rr < 8; rr++) acc[rr] += x1[rr][c] * wvv;
        }
        float* out = kq ? Qp : Kp;
#pragma unroll
        for (int rr = 0; rr < 8; rr++) out[(h * RR + r0 + rr) * D4 + tid] = acc[rr];
    } else {
        int vb = blk - 256;
        int r0 = vb * 32;
        __shared__ float sx[4][CC];
        for (int batch = 0; batch < 8; ++batch) {
            int row = r0 + batch * 4 + wv;
            float xv = x[row * CC + lane];
            float m = wred_sum(xv) * (1.f / CC);
            float d = xv - m;
            float var = wred_sum(d * d) * (1.f / CC);
            sx[wv][lane] = d * rsqrtf(var + 1e-5f) * ln1g[lane] + ln1b[lane];
            __syncthreads();
            int h = lane >> 4, sd = lane & 15;
            const float* wvw = valW + h * CC * SS;
            float a = 0.f;
            for (int k = 0; k < CC; k++) a += sx[wv][k] * wvw[k * SS + sd];
            v[(h * RR + row) * SS + sd] = a;
            __syncthreads();
        }
    }
}

// ================= stage B: attention (all 4 heads) + proj/FF/LNs, 1 block/row
__global__ void __launch_bounds__(256) k_stageB(
    const float* __restrict__ Kp, const float* __restrict__ Qp,
    const float* __restrict__ v,
    const float* __restrict__ ab1, const float* __restrict__ aw2,
    const float* __restrict__ ab2,
    float* __restrict__ x,
    const float* __restrict__ projW, const float* __restrict__ projb,
    const float* __restrict__ g2, const float* __restrict__ b2,
    const float* __restrict__ fW1, const float* __restrict__ fb1,
    const float* __restrict__ fW2, const float* __restrict__ fb2,
    const float* __restrict__ g3, const float* __restrict__ b3) {
    int row = blockIdx.x;
    int bb_ = row >> 7, i = row & 127;
    int tid = threadIdx.x, lane = tid & 63, h = tid >> 6;
    __shared__ __align__(16) float q_s[HH][D4];
    __shared__ __align__(16) float w2_s[HH][D4];
    __shared__ float sc[HH][TT];
    __shared__ float part[HH][4][SS];
    __shared__ float o_s[CC], s_x[CC], s_h[HID_], red[4][CC];
    for (int e = tid; e < HH * D4; e += 256) {
        int hh = e >> 8, d = e & 255;
        q_s[hh][d] = Qp[(hh * RR + row) * D4 + d] + ab1[hh * D4 + d];
        w2_s[hh][d] = aw2[hh * D4 + d];
    }
    __syncthreads();
    // scores: each wave owns one head, serial over j
    float4 qq = *(const float4*)(&q_s[h][lane * 4]);
    float4 ww = *(const float4*)(&w2_s[h][lane * 4]);
    float b2s = ab2[h];
    const float* Kb = Kp + (h * RR + bb_ * TT) * D4;
    for (int j = 0; j <= i; ++j) {
        float4 kk = *(const float4*)(Kb + j * D4 + lane * 4);
        float a = sigm(qq.x + kk.x) * ww.x + sigm(qq.y + kk.y) * ww.y +
                  sigm(qq.z + kk.z) * ww.z + sigm(qq.w + kk.w) * ww.w;
        a = wred_sum(a);
        if (lane == 0) sc[h][j] = (a + b2s) * 0.125f;   // * C^-0.5
    }
    __syncthreads();
    // softmax per head (wave h handles head h)
    {
        float s0 = (lane <= i) ? sc[h][lane] : -1e30f;
        float s1 = (lane + 64 <= i) ? sc[h][lane + 64] : -1e30f;
        float m = wred_max(fmaxf(s0, s1));
        float e0 = (lane <= i) ? __expf(s0 - m) : 0.f;
        float e1 = (lane + 64 <= i) ? __expf(s1 - m) : 0.f;
        float inv = 1.f / wred_sum(e0 + e1);
        sc[h][lane] = e0 * inv;
        sc[h][lane + 64] = e1 * inv;
    }
    __syncthreads();
    // PV: wave h, 4-way j-parallel x 16 s
    {
        int jg = lane >> 4, s = lane & 15;
        const float* vb = v + (h * RR + bb_ * TT) * SS;
        float acc = 0.f;
        for (int j = jg; j <= i; j += 4) acc += sc[h][j] * vb[j * SS + s];
        part[h][jg][s] = acc;
    }
    __syncthreads();
    if (tid < CC) {
        int hh = tid >> 4, s = tid & 15;
        o_s[tid] = part[hh][0][s] + part[hh][1][s] + part[hh][2][s] + part[hh][3][s];
    }
    __syncthreads();
    // post: proj + residual + LN2 (wave 0)
    float xv = 0.f;
    if (tid < CC) {
        float acc = projb[tid];
        for (int k = 0; k < CC; k++) acc += o_s[k] * projW[k * CC + tid];
        xv = x[row * CC + tid] + acc;
        float m = wred_sum(xv) * (1.f / CC);
        float d = xv - m;
        float var = wred_sum(d * d) * (1.f / CC);
        s_x[tid] = d * rsqrtf(var + 1e-5f) * g2[tid] + b2[tid];
    }
    __syncthreads();
    // FF1: 256 threads = 256 hidden units
    {
        float a = fb1[tid];
        for (int k = 0; k < CC; k++) a += s_x[k] * fW1[k * HID_ + tid];
        s_h[tid] = sigm(a);
    }
    __syncthreads();
    // FF2: partial dots, 4 quarters
    {
        int c = tid & 63, q = tid >> 6;
        float acc = 0.f;
        for (int k = q * 64; k < q * 64 + 64; ++k) acc += s_h[k] * fW2[k * CC + c];
        red[q][c] = acc;
    }
    __syncthreads();
    if (tid < CC) {
        float f = fb2[tid] + red[0][tid] + red[1][tid] + red[2][tid] + red[3][tid];
        float x2 = xv + f;
        float m = wred_sum(x2) * (1.f / CC);
        float d = x2 - m;
        float var = wred_sum(d * d) * (1.f / CC);
        x[row * CC + tid] = d * rsqrtf(var + 1e-5f) * g3[tid] + b3[tid];
    }
}

// ================= lm_head: register-tiled skinny GEMM ======================
// block: 256 thr = 4 row-groups(waves) x 64 v-groups; thread tile 16r x 4v
// grid (125, 4): 256 v per block, 64 rows per block
__global__ void __launch_bounds__(256) k_lmhead(const float* __restrict__ x,
                                                const float* __restrict__ lmW,
                                                const float* __restrict__ lmb,
                                                float* __restrict__ out) {
    int lane = threadIdx.x & 63, wv = threadIdx.x >> 6;
    int vv = blockIdx.x * 256 + lane * 4;
    int r0 = __builtin_amdgcn_readfirstlane(blockIdx.y * 64 + wv * 16);
    const float* xb = x + r0 * CC;         // wave-uniform base -> scalar loads
    float4 bias = *(const float4*)(lmb + vv);
    float4 acc[16];
#pragma unroll
    for (int rr = 0; rr < 16; rr++) acc[rr] = bias;
#pragma unroll
    for (int ct = 0; ct < 4; ++ct) {       // c-tiles of 16
        float4 w4[16];
#pragma unroll
        for (int cc = 0; cc < 16; cc++)
            w4[cc] = *(const float4*)(lmW + (size_t)(ct * 16 + cc) * VV + vv);
#pragma unroll
        for (int rr = 0; rr < 16; rr++) {
#pragma unroll
            for (int cc = 0; cc < 16; cc++) {
                float xs = xb[rr * CC + ct * 16 + cc];
                acc[rr].x += xs * w4[cc].x;
                acc[rr].y += xs * w4[cc].y;
                acc[rr].z += xs * w4[cc].z;
                acc[rr].w += xs * w4[cc].w;
            }
        }
    }
#pragma unroll
    for (int rr = 0; rr < 16; rr++)
        *(float4*)(out + (size_t)(r0 + rr) * VV + vv) = acc[rr];
}

extern "C" void kernel_launch(void* const* d_in, const int* in_sizes, int n_in,
                              void* d_out, int out_size, void* d_ws, size_t ws_size,
                              hipStream_t stream) {
    const int*   idx   = (const int*)d_in[0];
    const float* tok   = (const float*)d_in[1];
    const float* petab = (const float*)d_in[2];
    const float* peW1  = (const float*)d_in[3];
    const float* peb1  = (const float*)d_in[4];
    const float* peW2  = (const float*)d_in[5];
    const float* peb2  = (const float*)d_in[6];
    const float* peg   = (const float*)d_in[7];
    const float* pebb  = (const float*)d_in[8];
    const float* ln1g  = (const float*)d_in[9];
    const float* ln1b  = (const float*)d_in[10];
    const float* attW1 = (const float*)d_in[11];
    const float* attb1 = (const float*)d_in[12];
    const float* attW2 = (const float*)d_in[13];
    const float* attb2 = (const float*)d_in[14];
    const float* valW  = (const float*)d_in[15];
    const float* projW = (const float*)d_in[16];
    const float* projb = (const float*)d_in[17];
    const float* ln2g  = (const float*)d_in[18];
    const float* ln2b  = (const float*)d_in[19];
    const float* ffW1  = (const float*)d_in[20];
    const float* ffb1  = (const float*)d_in[21];
    const float* ffW2  = (const float*)d_in[22];
    const float* ffb2  = (const float*)d_in[23];
    const float* ln3g  = (const float*)d_in[24];
    const float* ln3b  = (const float*)d_in[25];
    const float* lmW   = (const float*)d_in[26];
    const float* lmb   = (const float*)d_in[27];

    float* ws  = (float*)d_ws;
    float* x   = ws;                  // 16384
    float* pos = ws + 16384;          // 32768
    float* v   = ws + 49152;          // 16384
    float* Kp  = ws + 65536;          // 262144
    float* Qp  = ws + 327680;         // 262144

    k_embed_pos<<<768, CC, 0, stream>>>(idx, tok, petab, peW1, peb1, peW2, peb2,
                                        peg, pebb, x, pos);
    for (int p = 0; p < NPE_; p++) {
        k_stageA<<<264, 256, 0, stream>>>(x, pos + p * TT * CC, ln1g, ln1b,
                                          attW1, valW, Kp, Qp, v);
        k_stageB<<<256, 256, 0, stream>>>(Kp, Qp, v, attb1, attW2, attb2, x,
                                          projW, projb, ln2g, ln2b, ffW1, ffb1,
                                          ffW2, ffb2, ln3g, ln3b);
    }
    k_lmhead<<<dim3(125, 4), 256, 0, stream>>>(x, lmW, lmb, (float*)d_out);
}